// Round 5
// baseline (484.870 us; speedup 1.0000x reference)
//
#include <hip/hip_runtime.h>
#include <math.h>

// BondOrderConv: out[e] = sigmoid( nf[src[e]]·W_src + b_src
//                                + nf[dst[e]]·W_dst + b_dst
//                                + ef[e]·W_edge + b_edge )
// F = 256 f32. Memory-bound: ~343 MB stream -> floor ~54.5 us @ 6.3 TB/s.
//
// Journal:
//  R2: 16 lanes/row x 4 rows = 62.8 us (best two-kernel).
//  R3: cooperative fused launch -> 726 GB/s streaming (NEVER again).
//  R4: 8x8 layout -> 67.5 us (VGPR>64 occupancy cliff; many light waves win).
//  R5 (this): single persistent kernel, producer(node gates)->flag->consumer
//      (edge epilogue) with deferred fixup; nt loads on the ef stream.
//      Deadlock safety: __launch_bounds__(256,8) => VGPR<=64 => all 2048
//      blocks co-resident; node units are each producer-wave's FIRST unit.

#define FDIM 256
#define F4   64          // float4 per row

typedef float f32x4 __attribute__((ext_vector_type(4)));

__device__ __forceinline__ float dot4v(f32x4 a, f32x4 b) {
    return a[0] * b[0] + a[1] * b[1] + a[2] * b[2] + a[3] * b[3];
}

__global__ void __launch_bounds__(256, 8)
fused_persistent(const float* __restrict__ nf, const float* __restrict__ ef,
                 const int* __restrict__ src, const int* __restrict__ dst,
                 const float* __restrict__ W_src, const float* __restrict__ b_src,
                 const float* __restrict__ W_dst, const float* __restrict__ b_dst,
                 const float* __restrict__ W_edge, const float* __restrict__ b_edge,
                 float* __restrict__ e_src, float* __restrict__ e_dst,
                 float* __restrict__ gdef, int* __restrict__ ctr,
                 float* __restrict__ out,
                 int n_nodes, int n_edges, int ng_node, int n_units) {
    const int lane   = threadIdx.x & 63;
    const int sub    = lane >> 4;        // which of 4 rows in the unit
    const int i      = lane & 15;        // column lane within row
    const int wave   = (blockIdx.x * blockDim.x + threadIdx.x) >> 6;
    const int nwaves = (gridDim.x * blockDim.x) >> 6;

    // Edge weights live in registers for the whole kernel (hot path).
    const f32x4* We4 = reinterpret_cast<const f32x4*>(W_edge);
    const f32x4 w0 = We4[i], w1 = We4[i + 16], w2 = We4[i + 32], w3 = We4[i + 48];
    const float be = b_edge[0];

    bool ready = false;      // node gates globally visible
    bool any_defer = false;  // this wave stashed any edge unit
    int  k_ready = 0;        // iterations processed before ready
    int  k = 0;

    for (int u = wave; u < n_units; u += nwaves, ++k) {
        if (u < ng_node) {
            // ---- node unit: nodes 4u .. 4u+3 (producer; cold path) ----
            const int n = u * 4 + sub;
            if (n < n_nodes) {
                const f32x4* Ws4 = reinterpret_cast<const f32x4*>(W_src);
                const f32x4* Wd4 = reinterpret_cast<const f32x4*>(W_dst);
                const f32x4* row = reinterpret_cast<const f32x4*>(nf) + (size_t)n * F4;
                const f32x4 x0 = row[i], x1 = row[i + 16], x2 = row[i + 32], x3 = row[i + 48];
                float ss = dot4v(x0, Ws4[i])      + dot4v(x1, Ws4[i + 16])
                         + dot4v(x2, Ws4[i + 32]) + dot4v(x3, Ws4[i + 48]);
                float sd = dot4v(x0, Wd4[i])      + dot4v(x1, Wd4[i + 16])
                         + dot4v(x2, Wd4[i + 32]) + dot4v(x3, Wd4[i + 48]);
                #pragma unroll
                for (int off = 1; off < 16; off <<= 1) {
                    ss += __shfl_xor(ss, off, 64);
                    sd += __shfl_xor(sd, off, 64);
                }
                if (i == 0) {
                    e_src[n] = ss + b_src[0];
                    e_dst[n] = sd + b_dst[0];
                }
            }
            __threadfence();                       // release stores
            if (lane == 0) atomicAdd(ctr, 1);      // device-scope by default
            continue;
        }

        // ---- edge unit: edges 4g .. 4g+3 (the 327 MB stream) ----
        const int g = u - ng_node;
        const int e = g * 4 + sub;
        float s = 0.f;
        if (e < n_edges) {
            const f32x4* row = reinterpret_cast<const f32x4*>(ef) + (size_t)e * F4;
            const f32x4 x0 = __builtin_nontemporal_load(row + i);
            const f32x4 x1 = __builtin_nontemporal_load(row + i + 16);
            const f32x4 x2 = __builtin_nontemporal_load(row + i + 32);
            const f32x4 x3 = __builtin_nontemporal_load(row + i + 48);
            s = dot4v(x0, w0) + dot4v(x1, w1) + dot4v(x2, w2) + dot4v(x3, w3);
            #pragma unroll
            for (int off = 1; off < 16; off <<= 1) {
                s += __shfl_xor(s, off, 64);
            }
        }
        if (!ready) {
            if (__hip_atomic_load(ctr, __ATOMIC_RELAXED, __HIP_MEMORY_SCOPE_AGENT) >= ng_node) {
                __threadfence();                   // acquire: invalidate stale caches
                ready = true;
                k_ready = k;
            }
        }
        if (ready) {
            if (e < n_edges && i == 0) {
                const float m = s + be + e_src[src[e]] + e_dst[dst[e]];
                out[e] = 1.0f / (1.0f + expf(-m));
            }
        } else {
            if (e < n_edges && i == 0) gdef[e] = s + be;   // stash; fix up later
            any_defer = true;
        }
    }

    // ---- deferred fixup (typically k_ready<=1: ~7% of edges, all L2-hot) ----
    if (any_defer) {
        if (!ready) {
            while (__hip_atomic_load(ctr, __ATOMIC_RELAXED, __HIP_MEMORY_SCOPE_AGENT) < ng_node)
                __builtin_amdgcn_s_sleep(2);
            __threadfence();
            k_ready = k;
        }
        int kk = 0;
        for (int u = wave; kk < k_ready; u += nwaves, ++kk) {
            if (u < ng_node) continue;
            const int e = (u - ng_node) * 4 + sub;
            if (e < n_edges && i == 0) {
                const float m = gdef[e] + e_src[src[e]] + e_dst[dst[e]];
                out[e] = 1.0f / (1.0f + expf(-m));
            }
        }
    }
}

extern "C" void kernel_launch(void* const* d_in, const int* in_sizes, int n_in,
                              void* d_out, int out_size, void* d_ws, size_t ws_size,
                              hipStream_t stream) {
    const float* node_feats = (const float*)d_in[0];
    const float* edge_feats = (const float*)d_in[1];
    const int*   src        = (const int*)d_in[2];
    const int*   dst        = (const int*)d_in[3];
    const float* W_src      = (const float*)d_in[4];
    const float* b_src      = (const float*)d_in[5];
    const float* W_dst      = (const float*)d_in[6];
    const float* b_dst      = (const float*)d_in[7];
    const float* W_edge     = (const float*)d_in[8];
    const float* b_edge     = (const float*)d_in[9];

    const int n_nodes = in_sizes[0] / FDIM;
    const int n_edges = in_sizes[2];
    const int ng_node = (n_nodes + 3) / 4;
    const int ng_edge = (n_edges + 3) / 4;
    const int n_units = ng_node + ng_edge;

    // ws layout: [ctr (4B) | pad to 256B | e_src | e_dst | gdef]
    int*   ctr   = (int*)d_ws;
    float* e_src = (float*)((char*)d_ws + 256);
    float* e_dst = e_src + n_nodes;
    float* gdef  = e_dst + n_nodes;

    // ctr must be 0 at kernel start on EVERY call (ws not re-poisoned between
    // replays). 4-byte async memset is graph-capturable.
    hipMemsetAsync(d_ws, 0, 4, stream);

    // 2048 blocks x 256 thr = 8192 waves, all co-resident (launch_bounds 256,8
    // forces VGPR<=64 -> 8 blocks/CU x 256 CU). Required for the flag design.
    fused_persistent<<<2048, 256, 0, stream>>>(
        node_feats, edge_feats, src, dst,
        W_src, b_src, W_dst, b_dst, W_edge, b_edge,
        e_src, e_dst, gdef, ctr, (float*)d_out,
        n_nodes, n_edges, ng_node, n_units);
}

// Round 6
// 59.483 us; speedup vs baseline: 8.1515x; 8.1515x over previous
//
#include <hip/hip_runtime.h>
#include <math.h>

// BondOrderConv: out[e] = sigmoid( nf[src[e]]·W_src + b_src
//                                + nf[dst[e]]·W_dst + b_dst
//                                + ef[e]·W_edge + b_edge )
// F = 256 f32. Memory-bound: ~343 MB stream -> floor ~54.5 us @ 6.3 TB/s.
//
// Journal:
//  R2: 16 lanes/row x 4 rows, two kernels = 62.8 us (known-good backbone).
//  R3: cooperative fused launch -> 726 GB/s streaming. NEVER.
//  R4: 8x8 layout -> 67.5 us (VGPR>64 occupancy cliff; many light waves win).
//  R5: persistent producer->flag->consumer = 484 us. All-lane device-scope
//      atomic polling serializes at the coherence point (~1M far-atomics);
//      dispatch with ~0 HBM traffic still took 490 us. No in-kernel flags.
//  R6 (this): R2 backbone + explicit next-group prefetch in k2 (hide the
//      divergent lane-0 epilogue under next loads), nt loads on ef, __expf.
//      __launch_bounds__(256,8) pins VGPR <= 64 (stay on the fat side of the
//      occupancy cliff).

#define FDIM 256
#define F4   64          // float4 per row

typedef float f32x4 __attribute__((ext_vector_type(4)));

__device__ __forceinline__ float dot4v(f32x4 a, f32x4 b) {
    return a[0] * b[0] + a[1] * b[1] + a[2] * b[2] + a[3] * b[3];
}

// Kernel 1: per-node gate scalars (two dots per node). 10.2 MB, ~3 us.
__global__ void node_gates_kernel(const float* __restrict__ nf,
                                  const float* __restrict__ W_src,
                                  const float* __restrict__ W_dst,
                                  const float* __restrict__ b_src,
                                  const float* __restrict__ b_dst,
                                  float* __restrict__ e_src,
                                  float* __restrict__ e_dst,
                                  int n_nodes) {
    const int lane   = threadIdx.x & 63;
    const int sub    = lane >> 4;        // which of 4 nodes
    const int i      = lane & 15;        // column lane within node
    const int wave   = (blockIdx.x * blockDim.x + threadIdx.x) >> 6;
    const int nwaves = (gridDim.x * blockDim.x) >> 6;

    const f32x4* Ws4 = reinterpret_cast<const f32x4*>(W_src);
    const f32x4* Wd4 = reinterpret_cast<const f32x4*>(W_dst);
    const f32x4 ws0 = Ws4[i], ws1 = Ws4[i + 16], ws2 = Ws4[i + 32], ws3 = Ws4[i + 48];
    const f32x4 wd0 = Wd4[i], wd1 = Wd4[i + 16], wd2 = Wd4[i + 32], wd3 = Wd4[i + 48];
    const float bs = b_src[0];
    const float bd = b_dst[0];

    const int ngroups = (n_nodes + 3) >> 2;
    for (int g = wave; g < ngroups; g += nwaves) {
        const int n = g * 4 + sub;
        if (n >= n_nodes) continue;
        const f32x4* row = reinterpret_cast<const f32x4*>(nf) + (size_t)n * F4;
        const f32x4 x0 = row[i], x1 = row[i + 16], x2 = row[i + 32], x3 = row[i + 48];
        float ss = dot4v(x0, ws0) + dot4v(x1, ws1) + dot4v(x2, ws2) + dot4v(x3, ws3);
        float sd = dot4v(x0, wd0) + dot4v(x1, wd1) + dot4v(x2, wd2) + dot4v(x3, wd3);
        #pragma unroll
        for (int off = 1; off < 16; off <<= 1) {
            ss += __shfl_xor(ss, off, 64);
            sd += __shfl_xor(sd, off, 64);
        }
        if (i == 0) {
            e_src[n] = ss + bs;
            e_dst[n] = sd + bd;
        }
    }
}

// Kernel 2: per-edge gate + gather + sigmoid. 327 MB stream — the hot kernel.
// Software-pipelined: group g+1's loads issue before group g's reduce/epilogue.
__global__ void __launch_bounds__(256, 8)
edge_gate_kernel(const float* __restrict__ ef,
                 const int* __restrict__ src,
                 const int* __restrict__ dst,
                 const float* __restrict__ W_edge,
                 const float* __restrict__ b_edge,
                 const float* __restrict__ e_src,
                 const float* __restrict__ e_dst,
                 float* __restrict__ out,
                 int n_edges) {
    const int lane   = threadIdx.x & 63;
    const int sub    = lane >> 4;        // which of 4 edges
    const int i      = lane & 15;        // column lane within edge
    const int wave   = (blockIdx.x * blockDim.x + threadIdx.x) >> 6;
    const int nwaves = (gridDim.x * blockDim.x) >> 6;

    const f32x4* We4 = reinterpret_cast<const f32x4*>(W_edge);
    const f32x4 w0 = We4[i], w1 = We4[i + 16], w2 = We4[i + 32], w3 = We4[i + 48];
    const float be = b_edge[0];

    const f32x4* ef4 = reinterpret_cast<const f32x4*>(ef);
    const int ngroups = (n_edges + 3) >> 2;

    int g = wave;
    if (g >= ngroups) return;

    // Prologue: load group g.
    f32x4 x0, x1, x2, x3;
    {
        const int e = g * 4 + sub;
        if (e < n_edges) {
            const f32x4* row = ef4 + (size_t)e * F4;
            x0 = __builtin_nontemporal_load(row + i);
            x1 = __builtin_nontemporal_load(row + i + 16);
            x2 = __builtin_nontemporal_load(row + i + 32);
            x3 = __builtin_nontemporal_load(row + i + 48);
        } else {
            x0 = x1 = x2 = x3 = (f32x4)0.f;
        }
    }

    while (g < ngroups) {
        const int gn = g + nwaves;
        // Issue next group's loads EARLY — epilogue latency hides under them.
        f32x4 y0, y1, y2, y3;
        if (gn < ngroups) {
            const int en = gn * 4 + sub;
            if (en < n_edges) {
                const f32x4* row = ef4 + (size_t)en * F4;
                y0 = __builtin_nontemporal_load(row + i);
                y1 = __builtin_nontemporal_load(row + i + 16);
                y2 = __builtin_nontemporal_load(row + i + 32);
                y3 = __builtin_nontemporal_load(row + i + 48);
            } else {
                y0 = y1 = y2 = y3 = (f32x4)0.f;
            }
        }

        // Reduce current group.
        float s = dot4v(x0, w0) + dot4v(x1, w1) + dot4v(x2, w2) + dot4v(x3, w3);
        #pragma unroll
        for (int off = 1; off < 16; off <<= 1) {
            s += __shfl_xor(s, off, 64);
        }
        const int e = g * 4 + sub;
        if (i == 0 && e < n_edges) {
            const float m = s + be + e_src[src[e]] + e_dst[dst[e]];
            out[e] = 1.0f / (1.0f + __expf(-m));
        }

        g = gn;
        x0 = y0; x1 = y1; x2 = y2; x3 = y3;
    }
}

extern "C" void kernel_launch(void* const* d_in, const int* in_sizes, int n_in,
                              void* d_out, int out_size, void* d_ws, size_t ws_size,
                              hipStream_t stream) {
    const float* node_feats = (const float*)d_in[0];
    const float* edge_feats = (const float*)d_in[1];
    const int*   src        = (const int*)d_in[2];
    const int*   dst        = (const int*)d_in[3];
    const float* W_src      = (const float*)d_in[4];
    const float* b_src      = (const float*)d_in[5];
    const float* W_dst      = (const float*)d_in[6];
    const float* b_dst      = (const float*)d_in[7];
    const float* W_edge     = (const float*)d_in[8];
    const float* b_edge     = (const float*)d_in[9];

    const int n_nodes = in_sizes[0] / FDIM;
    const int n_edges = in_sizes[2];

    float* e_src = (float*)d_ws;
    float* e_dst = e_src + n_nodes;

    // Kernel 1: 2500 node-groups -> 625 blocks of 256 (4 waves each).
    {
        int ngroups = (n_nodes + 3) / 4;
        int blocks = (ngroups + 3) / 4;
        if (blocks > 2048) blocks = 2048;
        node_gates_kernel<<<blocks, 256, 0, stream>>>(
            node_feats, W_src, W_dst, b_src, b_dst, e_src, e_dst, n_nodes);
    }

    // Kernel 2: 80000 edge-groups over 8192 waves (~9.8 iterations each).
    {
        edge_gate_kernel<<<2048, 256, 0, stream>>>(
            edge_feats, src, dst, W_edge, b_edge, e_src, e_dst,
            (float*)d_out, n_edges);
    }
}